// Round 3
// baseline (946.262 us; speedup 1.0000x reference)
//
#include <hip/hip_runtime.h>

typedef _Float16 f16x8 __attribute__((ext_vector_type(8)));
typedef float f32x4 __attribute__((ext_vector_type(4)));

#define EPS 1e-5f

__device__ __forceinline__ short f2h(float x) {
    _Float16 h = (_Float16)x;   // round-to-nearest-even v_cvt_f16_f32
    union { _Float16 h; short s; } u;
    u.h = h;
    return u.s;
}

// ---------------------------------------------------------------------------
// prep: convert Wm -> WtM fp16 in chunked layout [l][c=k/8][f][8] so an MFMA
// B-fragment load (16 lanes x 16B, f-major) is 256B-contiguous / L2-coalesced.
// Wl -> WtF[f][k] fp16 (f padded to 48, row-major 896) for gemm_final.
// Zero the stats buffers. Runs every call (ws is re-poisoned).
// ---------------------------------------------------------------------------
__global__ void prep_kernel(const float* __restrict__ Wm, const float* __restrict__ Wl,
                            short* __restrict__ WtM, short* __restrict__ WtF,
                            float* __restrict__ stats) {
    const long T1 = 14L * 896 * 128;
    const long T2 = 48L * 896;
    const long T3 = 15L * 256;
    long i = (long)blockIdx.x * blockDim.x + threadIdx.x;
    if (i < T1) {
        long l = i / (896 * 128);
        long r = i % (896 * 128);
        long k = r >> 7;
        long f = r & 127;
        WtM[l * 114688 + (k >> 3) * 1024 + f * 8 + (k & 7)] = f2h(Wm[i]);
    } else if (i < T1 + T2) {
        long j = i - T1;
        long f = j / 896;
        long k = j % 896;
        WtF[j] = (f < 36) ? f2h(Wl[k * 36 + f]) : (short)0;
    } else if (i < T1 + T2 + T3) {
        stats[i - T1 - T2] = 0.0f;
    }
}

// ---------------------------------------------------------------------------
// layer0: h_lin[n,f] = b0[f] + sum_{k<21} x[idx[n,k/3], k%3] * W0[k,f]
// plus per-feature sum / sumsq accumulation. 16-node tiles, 1 barrier pair per
// tile. All fp32 — exact.
// ---------------------------------------------------------------------------
#define L0_NB 16
__global__ __launch_bounds__(256) void layer0_kernel(
        const float* __restrict__ x, const int* __restrict__ idx,
        const float* __restrict__ W0, const float* __restrict__ b0,
        float* __restrict__ hlin, float* __restrict__ stats, int N) {
    __shared__ float sW[21 * 128];
    __shared__ float sX[L0_NB * 21];
    __shared__ float sStat[256];
    const int tid = threadIdx.x;
    for (int i = tid; i < 21 * 128; i += 256) sW[i] = W0[i];
    const int f = tid & 127;
    const int half = tid >> 7;
    const float bf = b0[f];
    float s = 0.f, ss = 0.f;
    const int ntiles = (N + L0_NB - 1) / L0_NB;
    for (int t = blockIdx.x; t < ntiles; t += gridDim.x) {
        const int n0 = t * L0_NB;
        __syncthreads();
        for (int i = tid; i < L0_NB * 21; i += 256) {
            int ni = i / 21;
            int k = i - ni * 21;
            int j = k / 3;
            int c = k - j * 3;
            int n = n0 + ni;
            if (n >= N) n = N - 1;
            sX[i] = x[(long)idx[n * 7 + j] * 3 + c];
        }
        __syncthreads();
#pragma unroll
        for (int ni = 0; ni < 8; ++ni) {
            int node = n0 + half * 8 + ni;
            if (node >= N) break;   // per-thread, no barrier inside
            float acc = bf;
#pragma unroll
            for (int k = 0; k < 21; ++k)
                acc = fmaf(sX[(half * 8 + ni) * 21 + k], sW[k * 128 + f], acc);
            hlin[(long)node * 128 + f] = acc;
            s += acc;
            ss += acc * acc;
        }
    }
    __syncthreads();
    if (half == 1) { sStat[f] = s; sStat[128 + f] = ss; }
    __syncthreads();
    if (half == 0) {
        atomicAdd(&stats[f], s + sStat[f]);
        atomicAdd(&stats[128 + f], ss + sStat[128 + f]);
    }
}

// ---------------------------------------------------------------------------
// gemm_mid (BN-fused, 32-node tiles, depth-2 A-prefetch, direct-from-L2 B):
//   - sB LDS staging removed: B fragments are loaded per-wave straight from
//     WtM (L2-resident, 229KB/layer shared by all 1281 blocks) in the chunked
//     [c][f][8] layout -> each fragment load is 4x256B contiguous.
//   - LDS = sA (32x136 shorts) + sIdx + sAux ~ 11KB -> occupancy is VGPR-bound.
//   - idx hoisted to sIdx once per block (kills the idx->gather serial chain).
//   - av0/av1: statically-named depth-2 prefetch buffers (issue j+2 while
//     computing j) -> ~2 phases (>600cy) to cover the L3 gather latency.
// Wave w covers all 32 nodes x feats [w*32, w*32+32): acc[2 mi][2 ni].
// Numerically identical to the previous version (same op order).
// ---------------------------------------------------------------------------
__global__ __launch_bounds__(256, 4) void gemm_mid_kernel(
        const float* __restrict__ hprev, const int* __restrict__ idx,
        const short* __restrict__ Wt, const float* __restrict__ bvec,
        const float* __restrict__ g, const float* __restrict__ be,
        const float* __restrict__ statsIn,
        float* __restrict__ hlin, float* __restrict__ statsOut,
        int N, float invN) {
    __shared__ short sA[32 * 136];   // [node][k] for current j (+8 pad)
    __shared__ int   sIdx[32 * 7];
    __shared__ float sAux[256];      // sc|sh during staging; stats scratch later

    const int tid = threadIdx.x;
    const int wave = tid >> 6;
    const int lane = tid & 63;
    const int quad = lane >> 4;
    const int l16 = lane & 15;
    const int m0 = blockIdx.x * 32;
    const int t16 = tid >> 4;        // 0..15: staging row group
    const int fb = (tid & 15) * 8;   // fixed k-chunk for staging

    if (tid < 128) {
        float mu = statsIn[tid] * invN;
        float var = statsIn[128 + tid] * invN - mu * mu;
        float rs = rsqrtf(var + EPS);
        float sc = g[tid] * rs;
        sAux[tid] = sc;
        sAux[128 + tid] = be[tid] - mu * sc;
    }
    if (tid < 224) {
        long gg = (long)m0 * 7 + tid;
        long mx = (long)N * 7 - 1;
        sIdx[tid] = idx[gg < mx ? gg : mx];
    }
    __syncthreads();

    float scR[8], shR[8];
#pragma unroll
    for (int e = 0; e < 8; ++e) {
        scR[e] = sAux[fb + e];
        shR[e] = sAux[128 + fb + e];
    }

    f32x4 acc[2][2];
#pragma unroll
    for (int ni = 0; ni < 2; ++ni) {
        float bv = bvec[wave * 32 + ni * 16 + l16];
        acc[0][ni][0] = bv; acc[0][ni][1] = bv; acc[0][ni][2] = bv; acc[0][ni][3] = bv;
        acc[1][ni][0] = bv; acc[1][ni][1] = bv; acc[1][ni][2] = bv; acc[1][ni][3] = bv;
    }

    // staging rows for this thread (clamped only in the last block)
    int e0 = m0 + t16;      e0 = (e0 < N) ? t16      : (N - 1 - m0);
    int e1 = m0 + 16 + t16; e1 = (e1 < N) ? 16 + t16 : (N - 1 - m0);

    float4 av0[4], av1[4];   // statically-named depth-2 prefetch buffers

    auto issueA = [&](int j, float4 (&av)[4]) {
        long row0 = sIdx[e0 * 7 + j];
        long row1 = sIdx[e1 * 7 + j];
        const float* s0 = &hprev[row0 * 128 + fb];
        const float* s1 = &hprev[row1 * 128 + fb];
        av[0] = *(const float4*)s0;
        av[1] = *(const float4*)(s0 + 4);
        av[2] = *(const float4*)s1;
        av[3] = *(const float4*)(s1 + 4);
    };
    auto writeA = [&](const float4 (&av)[4]) {
#pragma unroll
        for (int it = 0; it < 2; ++it) {
            int nl = t16 + it * 16;
            float4 v0 = av[2 * it], v1 = av[2 * it + 1];
            union { short sh8[8]; f16x8 v; } u;
            u.sh8[0] = f2h(fmaxf(fmaf(v0.x, scR[0], shR[0]), 0.f));
            u.sh8[1] = f2h(fmaxf(fmaf(v0.y, scR[1], shR[1]), 0.f));
            u.sh8[2] = f2h(fmaxf(fmaf(v0.z, scR[2], shR[2]), 0.f));
            u.sh8[3] = f2h(fmaxf(fmaf(v0.w, scR[3], shR[3]), 0.f));
            u.sh8[4] = f2h(fmaxf(fmaf(v1.x, scR[4], shR[4]), 0.f));
            u.sh8[5] = f2h(fmaxf(fmaf(v1.y, scR[5], shR[5]), 0.f));
            u.sh8[6] = f2h(fmaxf(fmaf(v1.z, scR[6], shR[6]), 0.f));
            u.sh8[7] = f2h(fmaxf(fmaf(v1.w, scR[7], shR[7]), 0.f));
            *(f16x8*)&sA[nl * 136 + fb] = u.v;
        }
    };
    auto mfmaPhase = [&](int j) {
#pragma unroll
        for (int k0 = 0; k0 < 128; k0 += 32) {
            f16x8 a[2], b[2];
#pragma unroll
            for (int mi = 0; mi < 2; ++mi)
                a[mi] = *(const f16x8*)&sA[(mi * 16 + l16) * 136 + k0 + quad * 8];
            int c = j * 16 + (k0 >> 3) + quad;
#pragma unroll
            for (int ni = 0; ni < 2; ++ni)
                b[ni] = *(const f16x8*)&Wt[c * 1024 + (wave * 32 + ni * 16 + l16) * 8];
#pragma unroll
            for (int mi = 0; mi < 2; ++mi)
#pragma unroll
                for (int ni = 0; ni < 2; ++ni)
                    acc[mi][ni] = __builtin_amdgcn_mfma_f32_16x16x32_f16(a[mi], b[ni], acc[mi][ni], 0, 0, 0);
        }
    };

    issueA(0, av0);
    issueA(1, av1);

    // 7 unrolled steps, alternating static buffers (rule #20: no runtime index)
    __syncthreads(); writeA(av0); issueA(2, av0); __syncthreads(); mfmaPhase(0);
    __syncthreads(); writeA(av1); issueA(3, av1); __syncthreads(); mfmaPhase(1);
    __syncthreads(); writeA(av0); issueA(4, av0); __syncthreads(); mfmaPhase(2);
    __syncthreads(); writeA(av1); issueA(5, av1); __syncthreads(); mfmaPhase(3);
    __syncthreads(); writeA(av0); issueA(6, av0); __syncthreads(); mfmaPhase(4);
    __syncthreads(); writeA(av1);                 __syncthreads(); mfmaPhase(5);
    __syncthreads(); writeA(av0);                 __syncthreads(); mfmaPhase(6);

    // epilogue: store h_lin fp32, accumulate per-feature stats (sAux reused)
    __syncthreads();
    sAux[tid] = 0.f;
    __syncthreads();
#pragma unroll
    for (int ni = 0; ni < 2; ++ni) {
        int feat = wave * 32 + ni * 16 + l16;
        float s = 0.f, ss = 0.f;
#pragma unroll
        for (int mi = 0; mi < 2; ++mi) {
#pragma unroll
            for (int r = 0; r < 4; ++r) {
                int node = m0 + mi * 16 + quad * 4 + r;
                float v = acc[mi][ni][r];
                if (node < N) {
                    hlin[(long)node * 128 + feat] = v;
                    s += v;
                    ss += v * v;
                }
            }
        }
        atomicAdd(&sAux[feat], s);
        atomicAdd(&sAux[128 + feat], ss);
    }
    __syncthreads();
    if (tid < 128) {
        atomicAdd(&statsOut[tid], sAux[tid]);
        atomicAdd(&statsOut[128 + tid], sAux[128 + tid]);
    }
}

// ---------------------------------------------------------------------------
// gemm_final (BN-fused, software-pipelined):
//   out[N,36] = gather7(relu(bn(hprev)))[N,896] @ Wl + bl
// WtF: [48][896] fp16 (feats 36..47 zero). Block: 64 nodes, wave = 16 nodes x 48 feats.
// ---------------------------------------------------------------------------
__global__ __launch_bounds__(256) void gemm_final_kernel(
        const float* __restrict__ hprev, const int* __restrict__ idx,
        const short* __restrict__ WtF, const float* __restrict__ bl,
        const float* __restrict__ g, const float* __restrict__ be,
        const float* __restrict__ statsIn,
        float* __restrict__ out, int N, float invN) {
    __shared__ short sA[64 * 136];
    __shared__ short sB[48 * 136];
    __shared__ float sAux[256];

    const int tid = threadIdx.x;
    const int wave = tid >> 6;
    const int lane = tid & 63;
    const int quad = lane >> 4;
    const int l16 = lane & 15;
    const int m0 = blockIdx.x * 64;
    const int t16 = tid >> 4;
    const int fb = (tid & 15) * 8;

    if (tid < 128) {
        float mu = statsIn[tid] * invN;
        float var = statsIn[128 + tid] * invN - mu * mu;
        float rs = rsqrtf(var + EPS);
        float sc = g[tid] * rs;
        sAux[tid] = sc;
        sAux[128 + tid] = be[tid] - mu * sc;
    }
    __syncthreads();
    float scR[8], shR[8];
#pragma unroll
    for (int e = 0; e < 8; ++e) {
        scR[e] = sAux[fb + e];
        shR[e] = sAux[128 + fb + e];
    }

    f32x4 acc[3];
#pragma unroll
    for (int ni = 0; ni < 3; ++ni) {
        int feat = ni * 16 + l16;
        float bv = (feat < 36) ? bl[feat] : 0.f;
        acc[ni][0] = bv; acc[ni][1] = bv; acc[ni][2] = bv; acc[ni][3] = bv;
    }

    float4 av[8];
    f16x8 bv[3];

    auto issueA = [&](int j) {
#pragma unroll
        for (int it = 0; it < 4; ++it) {
            int nl = t16 + it * 16;
            int n = m0 + nl;
            n = (n < N) ? n : (N - 1);
            long row = idx[n * 7 + j];
            const float* src = &hprev[row * 128 + fb];
            av[2 * it]     = *(const float4*)src;
            av[2 * it + 1] = *(const float4*)(src + 4);
        }
    };
    auto issueB = [&](int j) {
#pragma unroll
        for (int it = 0; it < 3; ++it) {
            int ff = t16 + it * 16;
            bv[it] = *(const f16x8*)&WtF[(long)ff * 896 + j * 128 + fb];
        }
    };
    auto writeA = [&]() {
#pragma unroll
        for (int it = 0; it < 4; ++it) {
            int nl = t16 + it * 16;
            float4 v0 = av[2 * it], v1 = av[2 * it + 1];
            union { short sh8[8]; f16x8 v; } u;
            u.sh8[0] = f2h(fmaxf(fmaf(v0.x, scR[0], shR[0]), 0.f));
            u.sh8[1] = f2h(fmaxf(fmaf(v0.y, scR[1], shR[1]), 0.f));
            u.sh8[2] = f2h(fmaxf(fmaf(v0.z, scR[2], shR[2]), 0.f));
            u.sh8[3] = f2h(fmaxf(fmaf(v0.w, scR[3], shR[3]), 0.f));
            u.sh8[4] = f2h(fmaxf(fmaf(v1.x, scR[4], shR[4]), 0.f));
            u.sh8[5] = f2h(fmaxf(fmaf(v1.y, scR[5], shR[5]), 0.f));
            u.sh8[6] = f2h(fmaxf(fmaf(v1.z, scR[6], shR[6]), 0.f));
            u.sh8[7] = f2h(fmaxf(fmaf(v1.w, scR[7], shR[7]), 0.f));
            *(f16x8*)&sA[nl * 136 + fb] = u.v;
        }
    };
    auto writeB = [&]() {
#pragma unroll
        for (int it = 0; it < 3; ++it) {
            int ff = t16 + it * 16;
            *(f16x8*)&sB[ff * 136 + fb] = bv[it];
        }
    };

    issueB(0);
    issueA(0);

    for (int j = 0; j < 7; ++j) {
        __syncthreads();
        writeB();
        writeA();
        if (j < 6) {
            issueB(j + 1);
            issueA(j + 1);
        }
        __syncthreads();
#pragma unroll
        for (int k0 = 0; k0 < 128; k0 += 32) {
            f16x8 a = *(const f16x8*)&sA[(wave * 16 + l16) * 136 + k0 + quad * 8];
            f16x8 b[3];
#pragma unroll
            for (int ni = 0; ni < 3; ++ni)
                b[ni] = *(const f16x8*)&sB[(ni * 16 + l16) * 136 + k0 + quad * 8];
#pragma unroll
            for (int ni = 0; ni < 3; ++ni)
                acc[ni] = __builtin_amdgcn_mfma_f32_16x16x32_f16(a, b[ni], acc[ni], 0, 0, 0);
        }
    }

#pragma unroll
    for (int ni = 0; ni < 3; ++ni) {
        int feat = ni * 16 + l16;
        if (feat < 36) {
#pragma unroll
            for (int r = 0; r < 4; ++r) {
                int node = m0 + wave * 16 + quad * 4 + r;
                if (node < N) out[(long)node * 36 + feat] = acc[ni][r];
            }
        }
    }
}

// ---------------------------------------------------------------------------
extern "C" void kernel_launch(void* const* d_in, const int* in_sizes, int n_in,
                              void* d_out, int out_size, void* d_ws, size_t ws_size,
                              hipStream_t stream) {
    const float* x   = (const float*)d_in[0];
    const int*   idx = (const int*)d_in[1];
    const float* W0  = (const float*)d_in[2];
    const float* b0  = (const float*)d_in[3];
    const float* g0  = (const float*)d_in[4];
    const float* be0 = (const float*)d_in[5];
    const float* Wm  = (const float*)d_in[6];
    const float* bm  = (const float*)d_in[7];
    const float* gm  = (const float*)d_in[8];
    const float* bem = (const float*)d_in[9];
    const float* Wl  = (const float*)d_in[10];
    const float* bl  = (const float*)d_in[11];
    float* out = (float*)d_out;

    const int N = in_sizes[0] / 3;          // 40962
    const float invN = 1.0f / (float)N;

    char* ws = (char*)d_ws;
    size_t off = 0;
    auto alloc = [&](size_t bytes) -> void* {
        void* p = ws + off;
        off = (off + bytes + 255) & ~(size_t)255;
        return p;
    };
    short* WtM   = (short*)alloc(14UL * 128 * 896 * 2);
    short* WtF   = (short*)alloc(48UL * 896 * 2);
    float* stats = (float*)alloc(15UL * 256 * 4);
    float* hlinA = (float*)alloc((size_t)N * 128 * 4);
    float* hlinB = (float*)alloc((size_t)N * 128 * 4);

    {
        long total = 14L * 896 * 128 + 48L * 896 + 15L * 256;
        int blocks = (int)((total + 255) / 256);
        prep_kernel<<<blocks, 256, 0, stream>>>(Wm, Wl, WtM, WtF, stats);
    }

    layer0_kernel<<<1280, 256, 0, stream>>>(x, idx, W0, b0, hlinA, stats, N);

    const int gblocks_mid = (N + 31) / 32;   // 1281 blocks -> ~5 blocks/CU demand
    float* hin = hlinA;
    float* hout = hlinB;
    const float* gPrev = g0;
    const float* bePrev = be0;
    for (int L = 0; L < 14; ++L) {
        gemm_mid_kernel<<<gblocks_mid, 256, 0, stream>>>(
            hin, idx, WtM + (size_t)L * 128 * 896, bm + L * 128,
            gPrev, bePrev, stats + L * 256,
            hout, stats + (L + 1) * 256, N, invN);
        gPrev = gm + L * 128;
        bePrev = bem + L * 128;
        float* t = hin; hin = hout; hout = t;
    }

    const int gblocks_fin = (N + 63) / 64;
    gemm_final_kernel<<<gblocks_fin, 256, 0, stream>>>(
        hin, idx, WtF, bl, gm + 13 * 128, bem + 13 * 128, stats + 14 * 256,
        out, N, invN);
}